// Round 6
// baseline (292.283 us; speedup 1.0000x reference)
//
#include <hip/hip_runtime.h>
#include <math.h>

#define B_   64
#define S_   197
#define D_   768
#define H_   12
#define HD_  64
#define M_   (B_ * S_)     // 12608
#define MPAD 12672         // 99*128
#define KE   224           // padded contraction length over s (7*32)
#define BH_  (B_ * H_)     // 768
#define WSZ  ((size_t)D_ * D_)   // 589824
#define CW   776           // ctx LDS row stride (halfs): 388 dw % 32 = 4 -> 2-way only

typedef _Float16 half8_t __attribute__((ext_vector_type(8)));
typedef _Float16 half4_t __attribute__((ext_vector_type(4)));
typedef _Float16 half2_t __attribute__((ext_vector_type(2)));
typedef float floatx4 __attribute__((ext_vector_type(4)));

// async global->LDS DMA, 16B per lane; lptr must be wave-uniform (HW adds lane*16)
#define LDS_DMA16(gptr, lptr) \
  __builtin_amdgcn_global_load_lds((const __attribute__((address_space(1))) void*)(gptr), \
                                   (__attribute__((address_space(3))) void*)(lptr), 16, 0, 0)

// ---------------------------------------------------------------------------
// Merged prep + Y kernel (R2 version, verbatim).
// ---------------------------------------------------------------------------
__global__ __launch_bounds__(256) void prep_y_kernel(
    const float* __restrict__ X,
    const float* __restrict__ Wq, const float* __restrict__ Wk,
    const float* __restrict__ Wv, const float* __restrict__ Wo,
    const float* __restrict__ Ek, const float* __restrict__ Ev,
    _Float16* __restrict__ Xh,
    _Float16* __restrict__ Tcat, _Float16* __restrict__ To,
    float* __restrict__ esumK, float* __restrict__ esumV,
    _Float16* __restrict__ Ybuf)
{
    __shared__ _Float16 smem[KE * 66];   // 29568 B; aliased as f32 tile below
    const int bid = blockIdx.x, tid = threadIdx.x;

    int task, idx;
    if (bid < 9984) {
        const int q = bid / 13, r = bid - q * 13;
        if (r == 0) { task = 0; idx = q; }            // Y
        else        { task = 1; idx = 12 * q + r - 1; } // conv [0,9216)
    } else if (bid < 10272) { task = 1; idx = 9216 + (bid - 9984); }
    else if (bid < 12576)   { task = 2; idx = bid - 10272; }
    else                    { task = 3; idx = bid - 12576; }

    if (task == 1) {                       // X -> f16 (zero-pad rows to MPAD)
        const int i4 = (idx * 256 + tid) * 4;
        float4 v = make_float4(0.f, 0.f, 0.f, 0.f);
        if (i4 < M_ * D_) v = *(const float4*)&X[i4];
        half4_t o = { (_Float16)v.x, (_Float16)v.y, (_Float16)v.z, (_Float16)v.w };
        *(half4_t*)&Xh[i4] = o;
        return;
    }

    if (task == 2) {                       // weight transpose + convert
        float (*tile)[33] = (float (*)[33])smem;
        const int z = idx / 576, rem = idx % 576;
        const int bx = rem % 24, by = rem / 24;
        // z: 0->Wk, 1->Wv, 2->Wq (into Tcat), 3->Wo (into To)
        const float* W = (z == 0) ? Wk : (z == 1) ? Wv : (z == 2) ? Wq : Wo;
        _Float16* T = (z < 3) ? (Tcat + (size_t)z * WSZ) : To;
        const int n0 = bx * 32, k0 = by * 32;
        const int r = tid >> 3, c4 = (tid & 7) * 4;
        *(float4*)&tile[r][c4] = *(const float4*)&W[(size_t)(k0 + r) * D_ + n0 + c4];
        __syncthreads();
        half4_t o = { (_Float16)tile[c4 + 0][r], (_Float16)tile[c4 + 1][r],
                      (_Float16)tile[c4 + 2][r], (_Float16)tile[c4 + 3][r] };
        *(half4_t*)&T[(size_t)(n0 + r) * D_ + k0 + c4] = o;
        return;
    }

    if (task == 3) {                       // esum over s of E columns
        const float* E = idx ? Ev : Ek;
        float* es = idx ? esumV : esumK;
        if (tid < 64) {
            float acc = 0.f;
            for (int s = 0; s < S_; ++s) acc += E[s * 64 + tid];
            es[tid] = acc;
        }
        return;
    }

    // ----- task 0: Y[b] = E^T @ X_b  (rows [0,64)=Y_k, [64,128)=Y_v) -----
    _Float16* Xs = smem;                   // KE x 66 f16 tile of X_b columns
    const int b = idx / 12, n0 = (idx % 12) * 64;
    const int w = tid >> 6, lane = tid & 63;
    const int l15 = lane & 15, quad = lane >> 4;

    #pragma unroll
    for (int i = 0; i < 7; ++i) {
        const int s = i * 32 + (tid >> 3);
        const int d0 = (tid & 7) * 8;
        float4 v0 = make_float4(0.f, 0.f, 0.f, 0.f), v1 = v0;
        if (s < S_) {                      // guard: don't read past X (M_ rows)
            const float* src = &X[(size_t)(b * S_ + s) * D_ + n0 + d0];
            v0 = *(const float4*)src;
            v1 = *(const float4*)(src + 4);
        }
        const _Float16 h[8] = { (_Float16)v0.x, (_Float16)v0.y, (_Float16)v0.z,
                                (_Float16)v0.w, (_Float16)v1.x, (_Float16)v1.y,
                                (_Float16)v1.z, (_Float16)v1.w };
        #pragma unroll
        for (int jj = 0; jj < 4; ++jj) {
            half2_t t2 = { h[2 * jj], h[2 * jj + 1] };
            *(half2_t*)&Xs[s * 66 + d0 + 2 * jj] = t2;
        }
    }
    __syncthreads();

    floatx4 acc[2][4] = {};
    #pragma unroll
    for (int k7 = 0; k7 < 7; ++k7) {
        half8_t af[2];
        #pragma unroll
        for (int mi = 0; mi < 2; ++mi) {
            const int row = w * 32 + mi * 16 + l15;      // [0,128)
            const float* Esrc = (row < 64) ? Ek : Ev;
            const int er = row & 63;
            #pragma unroll
            for (int jj = 0; jj < 8; ++jj) {
                const int s = k7 * 32 + quad * 8 + jj;
                af[mi][jj] = (_Float16)((s < S_) ? Esrc[s * 64 + er] : 0.f);
            }
        }
        #pragma unroll
        for (int ni = 0; ni < 4; ++ni) {
            const int sb = k7 * 32 + quad * 8;
            half8_t bf;
            #pragma unroll
            for (int jj = 0; jj < 8; ++jj) bf[jj] = Xs[(sb + jj) * 66 + ni * 16 + l15];
            #pragma unroll
            for (int mi = 0; mi < 2; ++mi)
                acc[mi][ni] = __builtin_amdgcn_mfma_f32_16x16x32_f16(
                    af[mi], bf, acc[mi][ni], 0, 0, 0);
        }
    }

    #pragma unroll
    for (int mi = 0; mi < 2; ++mi)
        #pragma unroll
        for (int ni = 0; ni < 4; ++ni)
            #pragma unroll
            for (int i = 0; i < 4; ++i) {
                const int m_local = w * 32 + mi * 16 + quad * 4 + i;
                const int row = (m_local >> 6) * 4096 + b * 64 + (m_local & 63);
                Ybuf[(size_t)row * D_ + n0 + ni * 16 + l15] = (_Float16)acc[mi][ni][i];
            }
}

// ---------------------------------------------------------------------------
// Fused Q + PKV GEMM (R2 version, verbatim): 1008 blocks, 128x128 tile,
// BK=64, 2-phase LDS double-buffer with __syncthreads.
// ---------------------------------------------------------------------------
__global__ __launch_bounds__(256) void gemm_qpkv(
    const _Float16* __restrict__ Xh, const _Float16* __restrict__ Ybuf,
    const _Float16* __restrict__ Tcat,
    const float* __restrict__ bq, const float* __restrict__ bk,
    const float* __restrict__ bv,
    const float* __restrict__ esumK, const float* __restrict__ esumV,
    _Float16* __restrict__ Qh, _Float16* __restrict__ pk16,
    _Float16* __restrict__ pv16)
{
    __shared__ _Float16 sm[32768];   // 2 x (A 128x64 | B 128x64) = 64 KB
    const int bid = blockIdx.x;
    const _Float16 *A, *W;
    const float *bias, *esum;
    _Float16* O16;
    int m0, n0, rowb;
    if (bid < 624) {                 // Q
        const int xcd = bid & 7, t = bid >> 3;
        const int slot = t / 6, j = t - slot * 6;
        const int m_blk = slot * 8 + xcd;
        if (m_blk >= MPAD / 128) return;
        m0 = m_blk * 128; n0 = j * 128; rowb = m0;
        A = Xh; W = Tcat + 2 * WSZ + (size_t)n0 * D_;
        bias = bq; esum = nullptr; O16 = Qh;
    } else {                         // PKV
        const int b2 = bid - 624;
        const int xcd = b2 & 7, t = b2 >> 3;
        const int slot = t / 6, j = t - slot * 6;
        const int m_blk = slot * 8 + xcd;    // [0,64)
        m0 = m_blk * 128; n0 = j * 128;
        const bool pv = (m_blk >= 32);
        rowb = pv ? m0 - 4096 : m0;
        A = Ybuf; W = Tcat + (pv ? WSZ : 0) + (size_t)n0 * D_;
        bias = pv ? bv : bk; esum = pv ? esumV : esumK;
        O16 = pv ? pv16 : pk16;
    }

    const int tid = threadIdx.x;
    const int w = tid >> 6, lane = tid & 63;
    const int fr = lane & 15, quad = lane >> 4, f7 = lane & 7;
    const int l3 = lane >> 3;
    const int csrc = ((lane & 7) ^ l3) * 8;
    const int wm = (w >> 1) * 64, wn = (w & 1) * 64;

    const _Float16* Abase = A + (size_t)(m0 + w * 32 + l3) * D_ + csrc;
    const _Float16* Wbase = W + (size_t)(w * 32 + l3) * D_ + csrc;

    floatx4 acc[4][4] = {};

#define QPKV_STAGE(BUF, K0) \
    { _Pragma("unroll") \
      for (int j = 0; j < 4; ++j) { \
          LDS_DMA16(Abase + (size_t)(j * 8) * D_ + (K0), &sm[(BUF) * 16384 + w * 2048 + j * 512]); \
          LDS_DMA16(Wbase + (size_t)(j * 8) * D_ + (K0), &sm[(BUF) * 16384 + 8192 + w * 2048 + j * 512]); \
      } }

#define QPKV_COMPUTE(BUF) \
    { _Pragma("unroll") \
      for (int ksub = 0; ksub < 2; ++ksub) { \
          const int sa = ((ksub * 4 + quad) ^ f7) * 8; \
          half8_t af[4], bf[4]; \
          _Pragma("unroll") \
          for (int i = 0; i < 4; ++i) { \
              af[i] = *(const half8_t*)&sm[(BUF) * 16384 + (wm + i * 16 + fr) * 64 + sa]; \
              bf[i] = *(const half8_t*)&sm[(BUF) * 16384 + 8192 + (wn + i * 16 + fr) * 64 + sa]; \
          } \
          _Pragma("unroll") \
          for (int mi = 0; mi < 4; ++mi) \
              _Pragma("unroll") \
              for (int ni = 0; ni < 4; ++ni) \
                  acc[mi][ni] = __builtin_amdgcn_mfma_f32_16x16x32_f16( \
                      af[mi], bf[ni], acc[mi][ni], 0, 0, 0); \
      } }

    QPKV_STAGE(0, 0);
    __syncthreads();
    #pragma unroll
    for (int t = 0; t < 10; t += 2) {
        QPKV_STAGE(1, (t + 1) * 64);
        QPKV_COMPUTE(0);
        __syncthreads();
        QPKV_STAGE(0, (t + 2) * 64);
        QPKV_COMPUTE(1);
        __syncthreads();
    }
    QPKV_STAGE(1, 11 * 64);
    QPKV_COMPUTE(0);
    __syncthreads();
    QPKV_COMPUTE(1);   // final tile lives in buffer 1: [16384,32768), disjoint from ct

    float bval[4];
    #pragma unroll
    for (int ni = 0; ni < 4; ++ni)
        bval[ni] = bias[n0 + wn + ni * 16 + fr];

    // single epilogue: two-pass wave-private LDS transpose + half8 row stores
    _Float16* ct = &sm[w * 2176];   // 32 x 68, within [0,8704) -- buffer 0 region
    #pragma unroll
    for (int half = 0; half < 2; ++half) {
        #pragma unroll
        for (int mi2 = 0; mi2 < 2; ++mi2) {
            const int mi = half * 2 + mi2;
            float esv[4] = {1.f, 1.f, 1.f, 1.f};
            if (esum) {
                const float4 es4 = *(const float4*)&esum[mi * 16 + quad * 4];
                esv[0] = es4.x; esv[1] = es4.y; esv[2] = es4.z; esv[3] = es4.w;
            }
            #pragma unroll
            for (int ni = 0; ni < 4; ++ni)
                #pragma unroll
                for (int i = 0; i < 4; ++i)
                    ct[(mi2 * 16 + quad * 4 + i) * 68 + ni * 16 + fr] =
                        (_Float16)(acc[mi][ni][i] + esv[i] * bval[ni]);
        }
        #pragma unroll
        for (int pass = 0; pass < 4; ++pass) {
            const int rr = pass * 8 + (lane >> 3);
            const int cc = (lane & 7) * 8;
            const half8_t v = *(const half8_t*)&ct[rr * 68 + cc];
            *(half8_t*)&O16[(size_t)(rowb + wm + half * 32 + rr) * D_ + n0 + wn + cc] = v;
        }
    }
}

// ---------------------------------------------------------------------------
// FUSED attention + O-projection.  Grid 448 = 7 s-tiles x 64 batches,
// bid = st*64 + b so a batch's 7 blocks share an XCD (pk/pv L2 reuse).
// Phase 1: each wave computes 3 heads' attention for the block's 32 rows
// (QK/softmax/PV code identical to the old attn kernel) into LDS ctx
// [32][CW] (f16, same rounding point as the old CTXh global store).
// P scratch aliases the wave's LAST head's ctx columns (written after use).
// Phase 2: O-GEMM row panel: A = ctx (LDS), B = To streamed from L2
// (To = 1.2 MB, fits per-XCD L2), wave w owns output cols [w*192,w*192+192).
// Accumulation order matches the old gemm_o (k0 asc, ksub asc) -> bit-identical.
// ---------------------------------------------------------------------------
__global__ __launch_bounds__(256) void attn_o_kernel(
    const _Float16* __restrict__ Qh, const _Float16* __restrict__ pk16,
    const _Float16* __restrict__ pv16, const _Float16* __restrict__ To,
    const float* __restrict__ bo, float* __restrict__ O32)
{
    __shared__ _Float16 ctx[32 * CW];    // 49,664 B
    const int bid = blockIdx.x;
    const int b = bid & 63, st = bid >> 6;
    const int srow0 = st * 32;
    const int tid = threadIdx.x, w = tid >> 6, lane = tid & 63;
    const int l15 = lane & 15, quad = lane >> 4;

    // P scratch = ctx columns of this wave's last head (overwritten after use)
    _Float16* P = &ctx[(w * 3 + 2) * 64];

    // ---------------- phase 1: attention, 3 heads per wave ----------------
    for (int hh = 0; hh < 3; ++hh) {
        const int h = w * 3 + hh;
        const _Float16* pkB = pk16 + (size_t)(b * 64) * D_ + h * 64;
        const _Float16* pvB = pv16 + (size_t)(b * 64) * D_ + h * 64;
        const size_t qbase = (size_t)(b * S_) * D_ + h * HD_;

        half8_t bkf[4][2], bvf[4][2];
        #pragma unroll
        for (int ni = 0; ni < 4; ++ni)
            #pragma unroll
            for (int kk = 0; kk < 2; ++kk) {
                bkf[ni][kk] = *(const half8_t*)&pkB[(size_t)(ni * 16 + l15) * D_ + kk * 32 + quad * 8];
                #pragma unroll
                for (int jj = 0; jj < 8; ++jj)
                    bvf[ni][kk][jj] = pvB[(size_t)(kk * 32 + quad * 8 + jj) * D_ + ni * 16 + l15];
            }

        floatx4 acc[2][4] = {};
        #pragma unroll
        for (int kk = 0; kk < 2; ++kk) {
            half8_t aq[2];
            #pragma unroll
            for (int mi = 0; mi < 2; ++mi)
                aq[mi] = *(const half8_t*)
                    &Qh[qbase + (size_t)(srow0 + mi * 16 + l15) * D_ + kk * 32 + quad * 8];
            #pragma unroll
            for (int ni = 0; ni < 4; ++ni)
                #pragma unroll
                for (int mi = 0; mi < 2; ++mi)
                    acc[mi][ni] = __builtin_amdgcn_mfma_f32_16x16x32_f16(
                        aq[mi], bkf[ni][kk], acc[mi][ni], 0, 0, 0);
        }

        #pragma unroll
        for (int mi = 0; mi < 2; ++mi) {
            float p[4][4];
            #pragma unroll
            for (int i = 0; i < 4; ++i) {
                const float s0 = acc[mi][0][i] * 0.125f, s1 = acc[mi][1][i] * 0.125f;
                const float s2 = acc[mi][2][i] * 0.125f, s3 = acc[mi][3][i] * 0.125f;
                float mx = fmaxf(fmaxf(s0, s1), fmaxf(s2, s3));
                #pragma unroll
                for (int off = 1; off < 16; off <<= 1)
                    mx = fmaxf(mx, __shfl_xor(mx, off, 64));
                const float e0 = __expf(s0 - mx), e1 = __expf(s1 - mx);
                const float e2 = __expf(s2 - mx), e3 = __expf(s3 - mx);
                float sme = e0 + e1 + e2 + e3;
                #pragma unroll
                for (int off = 1; off < 16; off <<= 1)
                    sme += __shfl_xor(sme, off, 64);
                const float inv = 1.f / sme;
                p[0][i] = e0 * inv; p[1][i] = e1 * inv;
                p[2][i] = e2 * inv; p[3][i] = e3 * inv;
            }
            #pragma unroll
            for (int ni = 0; ni < 4; ++ni)
                #pragma unroll
                for (int i = 0; i < 4; ++i)
                    P[(mi * 16 + quad * 4 + i) * CW + ni * 16 + l15] = (_Float16)p[ni][i];
        }

        floatx4 accv[2][4] = {};
        #pragma unroll
        for (int kk = 0; kk < 2; ++kk) {
            half8_t ap[2];
            #pragma unroll
            for (int mi = 0; mi < 2; ++mi)
                ap[mi] = *(const half8_t*)&P[(mi * 16 + l15) * CW + kk * 32 + quad * 8];
            #pragma unroll
            for (int ni = 0; ni < 4; ++ni)
                #pragma unroll
                for (int mi = 0; mi < 2; ++mi)
                    accv[mi][ni] = __builtin_amdgcn_mfma_f32_16x16x32_f16(
                        ap[mi], bvf[ni][kk], accv[mi][ni], 0, 0, 0);
        }
        #pragma unroll
        for (int mi = 0; mi < 2; ++mi)
            #pragma unroll
            for (int ni = 0; ni < 4; ++ni)
                #pragma unroll
                for (int i = 0; i < 4; ++i)
                    ctx[(mi * 16 + quad * 4 + i) * CW + h * 64 + ni * 16 + l15] =
                        (_Float16)accv[mi][ni][i];
    }
    __syncthreads();

    // ---------------- phase 2: O-GEMM row panel ----------------
    float bval[12];
    #pragma unroll
    for (int nf = 0; nf < 12; ++nf)
        bval[nf] = bo[w * 192 + nf * 16 + l15];

    floatx4 oacc[2][12] = {};
    for (int k0 = 0; k0 < 12; ++k0) {
        #pragma unroll
        for (int ksub = 0; ksub < 2; ++ksub) {
            const int ka = k0 * 64 + ksub * 32 + quad * 8;
            half8_t af[2];
            #pragma unroll
            for (int mi = 0; mi < 2; ++mi)
                af[mi] = *(const half8_t*)&ctx[(mi * 16 + l15) * CW + ka];
            #pragma unroll
            for (int nf = 0; nf < 12; ++nf) {
                const half8_t bf = *(const half8_t*)
                    &To[(size_t)(w * 192 + nf * 16 + l15) * D_ + ka];
                #pragma unroll
                for (int mi = 0; mi < 2; ++mi)
                    oacc[mi][nf] = __builtin_amdgcn_mfma_f32_16x16x32_f16(
                        af[mi], bf, oacc[mi][nf], 0, 0, 0);
            }
        }
    }

    #pragma unroll
    for (int nf = 0; nf < 12; ++nf) {
        const int n = w * 192 + nf * 16 + l15;
        #pragma unroll
        for (int mi = 0; mi < 2; ++mi)
            #pragma unroll
            for (int i = 0; i < 4; ++i) {
                const int s = srow0 + mi * 16 + quad * 4 + i;
                if (s < S_)
                    O32[(size_t)(b * S_ + s) * D_ + n] = oacc[mi][nf][i] + bval[nf];
            }
    }
}

// ---------------------------------------------------------------------------
extern "C" void kernel_launch(void* const* d_in, const int* in_sizes, int n_in,
                              void* d_out, int out_size, void* d_ws, size_t ws_size,
                              hipStream_t stream) {
    const float* X   = (const float*)d_in[0];
    const float* Wq  = (const float*)d_in[1];
    const float* bq  = (const float*)d_in[2];
    const float* Wk  = (const float*)d_in[3];
    const float* bk  = (const float*)d_in[4];
    const float* Wv  = (const float*)d_in[5];
    const float* bv  = (const float*)d_in[6];
    const float* Wo  = (const float*)d_in[7];
    const float* bo  = (const float*)d_in[8];
    const float* E_k = (const float*)d_in[9];
    const float* E_v = (const float*)d_in[10];
    float* out = (float*)d_out;

    char* p = (char*)d_ws;
    _Float16* Xh   = (_Float16*)p; p += (size_t)MPAD * D_ * 2;
    _Float16* Tcat = (_Float16*)p; p += (size_t)3 * WSZ * 2;     // Wk,Wv,Wq
    _Float16* To   = (_Float16*)p; p += (size_t)WSZ * 2;
    _Float16* Qh   = (_Float16*)p; p += (size_t)MPAD * D_ * 2;
    float* esumK   = (float*)p;    p += 64 * sizeof(float);
    float* esumV   = (float*)p;    p += 64 * sizeof(float);
    _Float16* Ybuf = (_Float16*)p; p += (size_t)8192 * D_ * 2;
    _Float16* pk16 = (_Float16*)p; p += (size_t)4096 * D_ * 2;
    _Float16* pv16 = (_Float16*)p;

    prep_y_kernel<<<12578, 256, 0, stream>>>(X, Wq, Wk, Wv, Wo, E_k, E_v,
                                             Xh, Tcat, To, esumK, esumV, Ybuf);
    gemm_qpkv<<<1008, 256, 0, stream>>>(Xh, Ybuf, Tcat,
                                        bq, bk, bv, esumK, esumV,
                                        Qh, pk16, pv16);
    attn_o_kernel<<<448, 256, 0, stream>>>(Qh, pk16, pv16, To, bo, out);
}

// Round 7
// 196.538 us; speedup vs baseline: 1.4872x; 1.4872x over previous
//
#include <hip/hip_runtime.h>
#include <math.h>

#define B_   64
#define S_   197
#define D_   768
#define H_   12
#define HD_  64
#define M_   (B_ * S_)     // 12608
#define MPAD 12672         // 99*128
#define KE   224           // padded contraction length over s (7*32)
#define BH_  (B_ * H_)     // 768
#define WSZ  ((size_t)D_ * D_)   // 589824

typedef _Float16 half8_t __attribute__((ext_vector_type(8)));
typedef _Float16 half4_t __attribute__((ext_vector_type(4)));
typedef _Float16 half2_t __attribute__((ext_vector_type(2)));
typedef float floatx4 __attribute__((ext_vector_type(4)));

// async global->LDS DMA, 16B per lane; lptr must be wave-uniform (HW adds lane*16)
#define LDS_DMA16(gptr, lptr) \
  __builtin_amdgcn_global_load_lds((const __attribute__((address_space(1))) void*)(gptr), \
                                   (__attribute__((address_space(3))) void*)(lptr), 16, 0, 0)

// ---------------------------------------------------------------------------
// Prep kernel, 3098 blocks.  Y-blocks now ALSO write Xh (they already load
// and convert every element of X), deleting the 9504 dedicated conv blocks
// (-38.7 MB of X re-reads).
//   [0,768)      Y-blocks: Y[b] = E^T @ X_b  AND Xh = f16(X) for their slice
//   [768,3072)   weight transpose+convert (Wk,Wv,Wq -> Tcat; Wo -> To)
//   [3072,3096)  zero-pad Xh rows [M_,MPAD)
//   [3096,3098)  esumK / esumV
// ---------------------------------------------------------------------------
__global__ __launch_bounds__(256) void prep_y_kernel(
    const float* __restrict__ X,
    const float* __restrict__ Wq, const float* __restrict__ Wk,
    const float* __restrict__ Wv, const float* __restrict__ Wo,
    const float* __restrict__ Ek, const float* __restrict__ Ev,
    _Float16* __restrict__ Xh,
    _Float16* __restrict__ Tcat, _Float16* __restrict__ To,
    float* __restrict__ esumK, float* __restrict__ esumV,
    _Float16* __restrict__ Ybuf)
{
    __shared__ _Float16 smem[KE * 66];   // 29568 B; aliased as f32 tile below
    const int bid = blockIdx.x, tid = threadIdx.x;

    if (bid >= 768 && bid < 3072) {        // weight transpose + convert
        const int idx = bid - 768;
        float (*tile)[33] = (float (*)[33])smem;
        const int z = idx / 576, rem = idx % 576;
        const int bx = rem % 24, by = rem / 24;
        // z: 0->Wk, 1->Wv, 2->Wq (into Tcat), 3->Wo (into To)
        const float* W = (z == 0) ? Wk : (z == 1) ? Wv : (z == 2) ? Wq : Wo;
        _Float16* T = (z < 3) ? (Tcat + (size_t)z * WSZ) : To;
        const int n0 = bx * 32, k0 = by * 32;
        const int r = tid >> 3, c4 = (tid & 7) * 4;
        *(float4*)&tile[r][c4] = *(const float4*)&W[(size_t)(k0 + r) * D_ + n0 + c4];
        __syncthreads();
        half4_t o = { (_Float16)tile[c4 + 0][r], (_Float16)tile[c4 + 1][r],
                      (_Float16)tile[c4 + 2][r], (_Float16)tile[c4 + 3][r] };
        *(half4_t*)&T[(size_t)(n0 + r) * D_ + k0 + c4] = o;
        return;
    }

    if (bid >= 3096) {                     // esum over s of E columns
        const int idx = bid - 3096;
        const float* E = idx ? Ev : Ek;
        float* es = idx ? esumV : esumK;
        if (tid < 64) {
            float acc = 0.f;
            for (int s = 0; s < S_; ++s) acc += E[s * 64 + tid];
            es[tid] = acc;
        }
        return;
    }

    if (bid >= 3072) {                     // zero-pad Xh rows [M_, MPAD)
        const int idx = bid - 3072;
        const half8_t z8 = {};
        *(half8_t*)&Xh[(size_t)M_ * D_ + (size_t)(idx * 256 + tid) * 8] = z8;
        return;
    }

    // ----- Y task: Y[b] = E^T @ X_b, and Xh = f16(X) for this slice -----
    _Float16* Xs = smem;                   // KE x 66 f16 tile of X_b columns
    const int idx = bid;
    const int b = idx / 12, n0 = (idx % 12) * 64;
    const int w = tid >> 6, lane = tid & 63;
    const int l15 = lane & 15, quad = lane >> 4;

    #pragma unroll
    for (int i = 0; i < 7; ++i) {
        const int s = i * 32 + (tid >> 3);
        const int d0 = (tid & 7) * 8;
        float4 v0 = make_float4(0.f, 0.f, 0.f, 0.f), v1 = v0;
        if (s < S_) {                      // guard: don't read past X (M_ rows)
            const float* src = &X[(size_t)(b * S_ + s) * D_ + n0 + d0];
            v0 = *(const float4*)src;
            v1 = *(const float4*)(src + 4);
        }
        const half8_t h8 = { (_Float16)v0.x, (_Float16)v0.y, (_Float16)v0.z,
                             (_Float16)v0.w, (_Float16)v1.x, (_Float16)v1.y,
                             (_Float16)v1.z, (_Float16)v1.w };
        if (s < S_)                        // conv output (was the conv task)
            *(half8_t*)&Xh[(size_t)(b * S_ + s) * D_ + n0 + d0] = h8;
        #pragma unroll
        for (int jj = 0; jj < 4; ++jj) {
            half2_t t2 = { h8[2 * jj], h8[2 * jj + 1] };
            *(half2_t*)&Xs[s * 66 + d0 + 2 * jj] = t2;
        }
    }
    __syncthreads();

    floatx4 acc[2][4] = {};
    #pragma unroll
    for (int k7 = 0; k7 < 7; ++k7) {
        half8_t af[2];
        #pragma unroll
        for (int mi = 0; mi < 2; ++mi) {
            const int row = w * 32 + mi * 16 + l15;      // [0,128)
            const float* Esrc = (row < 64) ? Ek : Ev;
            const int er = row & 63;
            #pragma unroll
            for (int jj = 0; jj < 8; ++jj) {
                const int s = k7 * 32 + quad * 8 + jj;
                af[mi][jj] = (_Float16)((s < S_) ? Esrc[s * 64 + er] : 0.f);
            }
        }
        #pragma unroll
        for (int ni = 0; ni < 4; ++ni) {
            const int sb = k7 * 32 + quad * 8;
            half8_t bf;
            #pragma unroll
            for (int jj = 0; jj < 8; ++jj) bf[jj] = Xs[(sb + jj) * 66 + ni * 16 + l15];
            #pragma unroll
            for (int mi = 0; mi < 2; ++mi)
                acc[mi][ni] = __builtin_amdgcn_mfma_f32_16x16x32_f16(
                    af[mi], bf, acc[mi][ni], 0, 0, 0);
        }
    }

    #pragma unroll
    for (int mi = 0; mi < 2; ++mi)
        #pragma unroll
        for (int ni = 0; ni < 4; ++ni)
            #pragma unroll
            for (int i = 0; i < 4; ++i) {
                const int m_local = w * 32 + mi * 16 + quad * 4 + i;
                const int row = (m_local >> 6) * 4096 + b * 64 + (m_local & 63);
                Ybuf[(size_t)row * D_ + n0 + ni * 16 + l15] = (_Float16)acc[mi][ni][i];
            }
}

// ---------------------------------------------------------------------------
// Fused Q + PKV GEMM (R2 main loop, verbatim): 1008 blocks, 128x128 tile,
// BK=64, 2-phase LDS double-buffer.  NEW: pv blocks use a MIRRORED two-pass
// ct transpose (ct[n_local][m_local]) and store pvT[h*64+d][b*64+k] as
// contiguous half8 row segments -- same instruction count as the Q/pk
// epilogue, fully coalesced (unlike R4's strided half4 scatter).
// ---------------------------------------------------------------------------
__global__ __launch_bounds__(256) void gemm_qpkv(
    const _Float16* __restrict__ Xh, const _Float16* __restrict__ Ybuf,
    const _Float16* __restrict__ Tcat,
    const float* __restrict__ bq, const float* __restrict__ bk,
    const float* __restrict__ bv,
    const float* __restrict__ esumK, const float* __restrict__ esumV,
    _Float16* __restrict__ Qh, _Float16* __restrict__ pk16,
    _Float16* __restrict__ pvT)
{
    __shared__ _Float16 sm[32768];   // 2 x (A 128x64 | B 128x64) = 64 KB
    const int bid = blockIdx.x;
    const _Float16 *A, *W;
    const float *bias, *esum;
    _Float16* O16;
    int m0, n0, rowb;
    bool pvt = false;
    if (bid < 624) {                 // Q
        const int xcd = bid & 7, t = bid >> 3;
        const int slot = t / 6, j = t - slot * 6;
        const int m_blk = slot * 8 + xcd;
        if (m_blk >= MPAD / 128) return;
        m0 = m_blk * 128; n0 = j * 128; rowb = m0;
        A = Xh; W = Tcat + 2 * WSZ + (size_t)n0 * D_;
        bias = bq; esum = nullptr; O16 = Qh;
    } else {                         // PKV
        const int b2 = bid - 624;
        const int xcd = b2 & 7, t = b2 >> 3;
        const int slot = t / 6, j = t - slot * 6;
        const int m_blk = slot * 8 + xcd;    // [0,64)
        m0 = m_blk * 128; n0 = j * 128;
        const bool pv = (m_blk >= 32);
        pvt = pv;
        rowb = pv ? m0 - 4096 : m0;
        A = Ybuf; W = Tcat + (pv ? WSZ : 0) + (size_t)n0 * D_;
        bias = pv ? bv : bk; esum = pv ? esumV : esumK;
        O16 = pk16;
    }

    const int tid = threadIdx.x;
    const int w = tid >> 6, lane = tid & 63;
    const int fr = lane & 15, quad = lane >> 4, f7 = lane & 7;
    const int l3 = lane >> 3;
    const int csrc = ((lane & 7) ^ l3) * 8;
    const int wm = (w >> 1) * 64, wn = (w & 1) * 64;

    const _Float16* Abase = A + (size_t)(m0 + w * 32 + l3) * D_ + csrc;
    const _Float16* Wbase = W + (size_t)(w * 32 + l3) * D_ + csrc;

    floatx4 acc[4][4] = {};

#define QPKV_STAGE(BUF, K0) \
    { _Pragma("unroll") \
      for (int j = 0; j < 4; ++j) { \
          LDS_DMA16(Abase + (size_t)(j * 8) * D_ + (K0), &sm[(BUF) * 16384 + w * 2048 + j * 512]); \
          LDS_DMA16(Wbase + (size_t)(j * 8) * D_ + (K0), &sm[(BUF) * 16384 + 8192 + w * 2048 + j * 512]); \
      } }

#define QPKV_COMPUTE(BUF) \
    { _Pragma("unroll") \
      for (int ksub = 0; ksub < 2; ++ksub) { \
          const int sa = ((ksub * 4 + quad) ^ f7) * 8; \
          half8_t af[4], bf[4]; \
          _Pragma("unroll") \
          for (int i = 0; i < 4; ++i) { \
              af[i] = *(const half8_t*)&sm[(BUF) * 16384 + (wm + i * 16 + fr) * 64 + sa]; \
              bf[i] = *(const half8_t*)&sm[(BUF) * 16384 + 8192 + (wn + i * 16 + fr) * 64 + sa]; \
          } \
          _Pragma("unroll") \
          for (int mi = 0; mi < 4; ++mi) \
              _Pragma("unroll") \
              for (int ni = 0; ni < 4; ++ni) \
                  acc[mi][ni] = __builtin_amdgcn_mfma_f32_16x16x32_f16( \
                      af[mi], bf[ni], acc[mi][ni], 0, 0, 0); \
      } }

    QPKV_STAGE(0, 0);
    __syncthreads();
    #pragma unroll
    for (int t = 0; t < 10; t += 2) {
        QPKV_STAGE(1, (t + 1) * 64);
        QPKV_COMPUTE(0);
        __syncthreads();
        QPKV_STAGE(0, (t + 2) * 64);
        QPKV_COMPUTE(1);
        __syncthreads();
    }
    QPKV_STAGE(1, 11 * 64);
    QPKV_COMPUTE(0);
    __syncthreads();
    QPKV_COMPUTE(1);   // final tile lives in buffer 1: [16384,32768), disjoint from ct

    float bval[4];
    #pragma unroll
    for (int ni = 0; ni < 4; ++ni)
        bval[ni] = bias[n0 + wn + ni * 16 + fr];

    _Float16* ct = &sm[w * 2176];   // 32 x 68, within [0,8704) -- buffer 0 region

    if (pvt) {
        // mirrored transpose: ct[n_local][m_local], halves over n
        #pragma unroll
        for (int half = 0; half < 2; ++half) {
            #pragma unroll
            for (int ni2 = 0; ni2 < 2; ++ni2) {
                const int ni = half * 2 + ni2;
                #pragma unroll
                for (int mi = 0; mi < 4; ++mi) {
                    const float4 es4 = *(const float4*)&esum[mi * 16 + quad * 4];
                    const float esv[4] = { es4.x, es4.y, es4.z, es4.w };
                    #pragma unroll
                    for (int i = 0; i < 4; ++i)
                        ct[(ni2 * 16 + fr) * 68 + mi * 16 + quad * 4 + i] =
                            (_Float16)(acc[mi][ni][i] + esv[i] * bval[ni]);
                }
            }
            #pragma unroll
            for (int pass = 0; pass < 4; ++pass) {
                const int rr = pass * 8 + (lane >> 3);    // 32 n-rows
                const int cc = (lane & 7) * 8;            // 64 m-cols
                const half8_t v = *(const half8_t*)&ct[rr * 68 + cc];
                *(half8_t*)&pvT[(size_t)(n0 + wn + half * 32 + rr) * 4096
                                + rowb + wm + cc] = v;
            }
        }
        return;
    }

    // Q / pk: two-pass wave-private LDS transpose + half8 row stores (R2)
    #pragma unroll
    for (int half = 0; half < 2; ++half) {
        #pragma unroll
        for (int mi2 = 0; mi2 < 2; ++mi2) {
            const int mi = half * 2 + mi2;
            float esv[4] = {1.f, 1.f, 1.f, 1.f};
            if (esum) {
                const float4 es4 = *(const float4*)&esum[mi * 16 + quad * 4];
                esv[0] = es4.x; esv[1] = es4.y; esv[2] = es4.z; esv[3] = es4.w;
            }
            #pragma unroll
            for (int ni = 0; ni < 4; ++ni)
                #pragma unroll
                for (int i = 0; i < 4; ++i)
                    ct[(mi2 * 16 + quad * 4 + i) * 68 + ni * 16 + fr] =
                        (_Float16)(acc[mi][ni][i] + esv[i] * bval[ni]);
        }
        #pragma unroll
        for (int pass = 0; pass < 4; ++pass) {
            const int rr = pass * 8 + (lane >> 3);
            const int cc = (lane & 7) * 8;
            const half8_t v = *(const half8_t*)&ct[rr * 68 + cc];
            *(half8_t*)&O16[(size_t)(rowb + wm + half * 32 + rr) * D_ + n0 + wn + cc] = v;
        }
    }
}

// ---------------------------------------------------------------------------
// O-projection GEMM, 128x128 / BK=64, 2-phase dbuf (R2 version, verbatim).
// ---------------------------------------------------------------------------
__global__ __launch_bounds__(256) void gemm_o(
    const _Float16* __restrict__ CTX, const _Float16* __restrict__ To,
    const float* __restrict__ bo, float* __restrict__ O32)
{
    __shared__ _Float16 sm[32768];
    const int xcd = blockIdx.x & 7, t = blockIdx.x >> 3;
    const int slot = t / 6, j = t - slot * 6;
    const int m_blk = slot * 8 + xcd;
    if (m_blk >= MPAD / 128) return;
    const int m0 = m_blk * 128, n0 = j * 128;

    const int tid = threadIdx.x;
    const int w = tid >> 6, lane = tid & 63;
    const int fr = lane & 15, quad = lane >> 4, f7 = lane & 7;
    const int l3 = lane >> 3;
    const int csrc = ((lane & 7) ^ l3) * 8;
    const int wm = (w >> 1) * 64, wn = (w & 1) * 64;

    const _Float16* Abase = CTX + (size_t)(m0 + w * 32 + l3) * D_ + csrc;
    const _Float16* Wbase = To + (size_t)(n0 + w * 32 + l3) * D_ + csrc;

    floatx4 acc[4][4] = {};

    QPKV_STAGE(0, 0);
    __syncthreads();
    #pragma unroll
    for (int t2 = 0; t2 < 10; t2 += 2) {
        QPKV_STAGE(1, (t2 + 1) * 64);
        QPKV_COMPUTE(0);
        __syncthreads();
        QPKV_STAGE(0, (t2 + 2) * 64);
        QPKV_COMPUTE(1);
        __syncthreads();
    }
    QPKV_STAGE(1, 11 * 64);
    QPKV_COMPUTE(0);
    __syncthreads();
    QPKV_COMPUTE(1);

    float bval[4];
    #pragma unroll
    for (int ni = 0; ni < 4; ++ni)
        bval[ni] = bo[n0 + wn + ni * 16 + fr];

    const bool full = (m0 + 128 <= M_);
    #pragma unroll
    for (int ni = 0; ni < 4; ++ni) {
        const int n = n0 + wn + ni * 16 + fr;
        #pragma unroll
        for (int mi = 0; mi < 4; ++mi)
            #pragma unroll
            for (int i = 0; i < 4; ++i) {
                const int m = m0 + wm + mi * 16 + quad * 4 + i;
                if (full || m < M_)
                    O32[(size_t)m * D_ + n] = acc[mi][ni][i] + bval[ni];
            }
    }
}

// ---------------------------------------------------------------------------
// MFMA attention: one block per (b,h), barrier-free.  V B-frags now read
// from pvT via 8 coalesced b128 loads (was 64 strided scalar u16 / thread).
// ---------------------------------------------------------------------------
__global__ __launch_bounds__(256) void attn_kernel(
    const _Float16* __restrict__ Qh, const _Float16* __restrict__ pk16,
    const _Float16* __restrict__ pvT, _Float16* __restrict__ CTXh)
{
    __shared__ _Float16 P[64 * 80];
    const int bh = blockIdx.x, b = bh / H_, h = bh % H_;
    const int tid = threadIdx.x, w = tid >> 6, lane = tid & 63;
    const int l15 = lane & 15, quad = lane >> 4;
    const _Float16* pkB = pk16 + (size_t)(b * 64) * D_ + h * 64;
    const _Float16* pvB = pvT + (size_t)(h * 64) * 4096 + b * 64;
    const size_t qbase = (size_t)(b * S_) * D_ + h * HD_;

    half8_t bkf[4][2], bvf[4][2];
    #pragma unroll
    for (int ni = 0; ni < 4; ++ni)
        #pragma unroll
        for (int kk = 0; kk < 2; ++kk) {
            bkf[ni][kk] = *(const half8_t*)&pkB[(size_t)(ni * 16 + l15) * D_ + kk * 32 + quad * 8];
            bvf[ni][kk] = *(const half8_t*)&pvB[(size_t)(ni * 16 + l15) * 4096 + kk * 32 + quad * 8];
        }

    for (int t = w; t < 13; t += 4) {
        const int srow = t * 16;
        floatx4 acc[4] = {};
        #pragma unroll
        for (int kk = 0; kk < 2; ++kk) {
            const half8_t aq = *(const half8_t*)
                &Qh[qbase + (size_t)(srow + l15) * D_ + kk * 32 + quad * 8];
            #pragma unroll
            for (int ni = 0; ni < 4; ++ni)
                acc[ni] = __builtin_amdgcn_mfma_f32_16x16x32_f16(
                    aq, bkf[ni][kk], acc[ni], 0, 0, 0);
        }
        float p[4][4];
        #pragma unroll
        for (int i = 0; i < 4; ++i) {
            const float s0 = acc[0][i] * 0.125f, s1 = acc[1][i] * 0.125f;
            const float s2 = acc[2][i] * 0.125f, s3 = acc[3][i] * 0.125f;
            float mx = fmaxf(fmaxf(s0, s1), fmaxf(s2, s3));
            #pragma unroll
            for (int off = 1; off < 16; off <<= 1)
                mx = fmaxf(mx, __shfl_xor(mx, off, 64));
            const float e0 = __expf(s0 - mx), e1 = __expf(s1 - mx);
            const float e2 = __expf(s2 - mx), e3 = __expf(s3 - mx);
            float sme = e0 + e1 + e2 + e3;
            #pragma unroll
            for (int off = 1; off < 16; off <<= 1)
                sme += __shfl_xor(sme, off, 64);
            const float inv = 1.f / sme;
            p[0][i] = e0 * inv; p[1][i] = e1 * inv;
            p[2][i] = e2 * inv; p[3][i] = e3 * inv;
        }
        #pragma unroll
        for (int ni = 0; ni < 4; ++ni)
            #pragma unroll
            for (int i = 0; i < 4; ++i)
                P[(w * 16 + quad * 4 + i) * 80 + ni * 16 + l15] = (_Float16)p[ni][i];

        floatx4 accv[4] = {};
        #pragma unroll
        for (int kk = 0; kk < 2; ++kk) {
            const half8_t ap = *(const half8_t*)&P[(w * 16 + l15) * 80 + kk * 32 + quad * 8];
            #pragma unroll
            for (int ni = 0; ni < 4; ++ni)
                accv[ni] = __builtin_amdgcn_mfma_f32_16x16x32_f16(
                    ap, bvf[ni][kk], accv[ni], 0, 0, 0);
        }
        #pragma unroll
        for (int ni = 0; ni < 4; ++ni)
            #pragma unroll
            for (int i = 0; i < 4; ++i) {
                const int s = srow + quad * 4 + i;
                if (s < S_)
                    CTXh[qbase + (size_t)s * D_ + ni * 16 + l15] = (_Float16)accv[ni][i];
            }
    }
}

// ---------------------------------------------------------------------------
extern "C" void kernel_launch(void* const* d_in, const int* in_sizes, int n_in,
                              void* d_out, int out_size, void* d_ws, size_t ws_size,
                              hipStream_t stream) {
    const float* X   = (const float*)d_in[0];
    const float* Wq  = (const float*)d_in[1];
    const float* bq  = (const float*)d_in[2];
    const float* Wk  = (const float*)d_in[3];
    const float* bk  = (const float*)d_in[4];
    const float* Wv  = (const float*)d_in[5];
    const float* bv  = (const float*)d_in[6];
    const float* Wo  = (const float*)d_in[7];
    const float* bo  = (const float*)d_in[8];
    const float* E_k = (const float*)d_in[9];
    const float* E_v = (const float*)d_in[10];
    float* out = (float*)d_out;

    char* p = (char*)d_ws;
    _Float16* Xh   = (_Float16*)p; p += (size_t)MPAD * D_ * 2;   // reused as CTXh
    _Float16* Tcat = (_Float16*)p; p += (size_t)3 * WSZ * 2;     // Wk,Wv,Wq
    _Float16* To   = (_Float16*)p; p += (size_t)WSZ * 2;
    _Float16* Qh   = (_Float16*)p; p += (size_t)MPAD * D_ * 2;
    float* esumK   = (float*)p;    p += 64 * sizeof(float);
    float* esumV   = (float*)p;    p += 64 * sizeof(float);
    _Float16* Ybuf = (_Float16*)p; p += (size_t)8192 * D_ * 2;
    _Float16* pk16 = (_Float16*)p; p += (size_t)4096 * D_ * 2;
    _Float16* pvT  = (_Float16*)p;   // [768][4096] f16

    prep_y_kernel<<<3098, 256, 0, stream>>>(X, Wq, Wk, Wv, Wo, E_k, E_v,
                                            Xh, Tcat, To, esumK, esumV, Ybuf);
    gemm_qpkv<<<1008, 256, 0, stream>>>(Xh, Ybuf, Tcat,
                                        bq, bk, bv, esumK, esumV,
                                        Qh, pk16, pvT);
    attn_kernel<<<BH_, 256, 0, stream>>>(Qh, pk16, pvT, Xh);
    gemm_o<<<624, 256, 0, stream>>>(Xh, To, bo, out);
}